// Round 2
// baseline (1443.547 us; speedup 1.0000x reference)
//
#include <hip/hip_runtime.h>
#include <hip/hip_bf16.h>
#include <math.h>

// Problem dims
#define SDIM 256
#define HDIM 768
#define EDIM 1536
#define NDIM 16
#define KCONV 4
#define RDIM 48
#define NLAYER 2
#define LSEQ 1024

#define NCHUNK 16
#define CHLEN (LSEQ / NCHUNK)   // 64

__device__ __forceinline__ float softplusf(float x) {
    return (x > 20.f) ? x : log1pf(expf(x));
}
__device__ __forceinline__ float siluf(float x) {
    return x / (1.f + expf(-x));
}

// ---------------- Generic tiled NT GEMM: out[M,N] = A[M,K] @ W[N,K]^T ----------------
// All fp32. Optional bias + softplus epilogue.
#define TS 64
#define KT 16

template<bool BIAS, bool SOFTPLUS>
__global__ __launch_bounds__(256) void gemm_nt(
    const float* __restrict__ A, int lda,
    const float* __restrict__ W, int ldw,
    const float* __restrict__ bias,
    float* __restrict__ out, int M, int N, int Kd)
{
    __shared__ float As[KT][TS + 4];
    __shared__ float Ws[KT][TS + 4];
    const int tid = threadIdx.x;
    const int tx = tid & 15, ty = tid >> 4;
    const int tx4 = tx * 4, ty4 = ty * 4;
    const int row0 = blockIdx.y * TS, col0 = blockIdx.x * TS;

    float acc[4][4] = {};

    for (int k0 = 0; k0 < Kd; k0 += KT) {
        #pragma unroll
        for (int i = 0; i < 4; i++) {
            int idx = tid + i * 256;
            int m = idx >> 4, kk = idx & 15;
            int gm = row0 + m, gk = k0 + kk;
            float v = 0.f;
            if (gm < M && gk < Kd) v = A[(size_t)gm * lda + gk];
            As[kk][m] = v;
        }
        #pragma unroll
        for (int i = 0; i < 4; i++) {
            int idx = tid + i * 256;
            int nn = idx >> 4, kk = idx & 15;
            int gn = col0 + nn, gk = k0 + kk;
            float v = 0.f;
            if (gn < N && gk < Kd) v = W[(size_t)gn * ldw + gk];
            Ws[kk][nn] = v;
        }
        __syncthreads();
        #pragma unroll
        for (int kk = 0; kk < KT; kk++) {
            float a[4], b[4];
            #pragma unroll
            for (int i = 0; i < 4; i++) a[i] = As[kk][ty4 + i];
            #pragma unroll
            for (int j = 0; j < 4; j++) b[j] = Ws[kk][tx4 + j];
            #pragma unroll
            for (int i = 0; i < 4; i++)
                #pragma unroll
                for (int j = 0; j < 4; j++)
                    acc[i][j] += a[i] * b[j];
        }
        __syncthreads();
    }

    #pragma unroll
    for (int i = 0; i < 4; i++) {
        int gm = row0 + ty4 + i;
        if (gm >= M) continue;
        #pragma unroll
        for (int j = 0; j < 4; j++) {
            int gn = col0 + tx4 + j;
            if (gn >= N) continue;
            float v = acc[i][j];
            if (BIAS) v += bias[gn];
            if (SOFTPLUS) v = softplusf(v);
            out[(size_t)gm * N + gn] = v;
        }
    }
}

// ---------------- Residual add + RMSNorm ----------------
// res = h (first) or res + h;  hn = res * rsqrt(mean(res^2)+eps) * w
__global__ __launch_bounds__(256) void rmsnorm_res(
    const float* __restrict__ h, float* __restrict__ res, float* __restrict__ hn,
    const float* __restrict__ w, int first)
{
    const int t = blockIdx.x;
    const int tid = threadIdx.x;
    float v[3];
    float ss = 0.f;
    #pragma unroll
    for (int r = 0; r < 3; r++) {
        int j = tid + r * 256;
        float x = h[(size_t)t * HDIM + j];
        if (!first) x += res[(size_t)t * HDIM + j];
        v[r] = x;
        res[(size_t)t * HDIM + j] = x;
        ss += x * x;
    }
    // wave reduce (width 64)
    #pragma unroll
    for (int m = 32; m >= 1; m >>= 1) ss += __shfl_down(ss, m);
    __shared__ float red[4];
    int wid = tid >> 6;
    if ((tid & 63) == 0) red[wid] = ss;
    __syncthreads();
    __shared__ float stot;
    if (tid == 0) stot = red[0] + red[1] + red[2] + red[3];
    __syncthreads();
    float scale = rsqrtf(stot / (float)HDIM + 1e-5f);
    #pragma unroll
    for (int r = 0; r < 3; r++) {
        int j = tid + r * 256;
        hn[(size_t)t * HDIM + j] = v[r] * scale * w[j];
    }
}

// ---------------- Depthwise causal conv1d + SiLU ----------------
// u[t,e] = silu(sum_k cw[e,k]*xin[t-3+k,e] + cb[e]); xin = xz[:, :E] (stride 2E)
__global__ __launch_bounds__(256) void conv_silu(
    const float* __restrict__ xz, const float* __restrict__ cw,
    const float* __restrict__ cb, float* __restrict__ u)
{
    const int e = blockIdx.x * 256 + threadIdx.x;
    const int t = blockIdx.y;
    float s = cb[e];
    #pragma unroll
    for (int k = 0; k < KCONV; k++) {
        int tt = t - (KCONV - 1) + k;
        if (tt >= 0) s += cw[e * KCONV + k] * xz[(size_t)tt * (2 * EDIM) + e];
    }
    u[(size_t)t * EDIM + e] = siluf(s);
}

// ---------------- Selective scan, chunked ----------------
// pass1: per-chunk local scan from zero init -> chunkS[c,e,n]; also sumdt[c,e]
__global__ __launch_bounds__(256) void scan_pass1(
    const float* __restrict__ dt, const float* __restrict__ u,
    const float* __restrict__ dbc, const float* __restrict__ a_log,
    float* __restrict__ chunkS, float* __restrict__ sumdt)
{
    const int tid = threadIdx.x;
    const int n = tid & 15, el = tid >> 4;
    const int e = blockIdx.x * 16 + el;
    const int c = blockIdx.y;
    const float Aen = -expf(a_log[e * NDIM + n]);
    float s = 0.f, sd = 0.f;
    const int t0 = c * CHLEN;
    for (int t = t0; t < t0 + CHLEN; t++) {
        float dtv = dt[(size_t)t * EDIM + e];
        float uv  = u[(size_t)t * EDIM + e];
        float Bv  = dbc[(size_t)t * 80 + RDIM + n];
        s = s * expf(dtv * Aen) + dtv * Bv * uv;
        sd += dtv;
    }
    chunkS[((size_t)c * EDIM + e) * NDIM + n] = s;
    if (n == 0) sumdt[(size_t)c * EDIM + e] = sd;
}

// pass2: cross-chunk combine -> sInit[c,e,n] (initial state entering chunk c)
__global__ __launch_bounds__(256) void scan_pass2(
    const float* __restrict__ chunkS, const float* __restrict__ sumdt,
    const float* __restrict__ a_log, float* __restrict__ sInit)
{
    const int idx = blockIdx.x * 256 + threadIdx.x;  // 0..E*N-1
    const int n = idx & 15, e = idx >> 4;
    const float Aen = -expf(a_log[idx]);
    float s = 0.f;
    for (int c = 0; c < NCHUNK; c++) {
        sInit[((size_t)c * EDIM + e) * NDIM + n] = s;
        float P = expf(Aen * sumdt[(size_t)c * EDIM + e]);
        s = s * P + chunkS[((size_t)c * EDIM + e) * NDIM + n];
    }
}

// pass3: re-run chunk with correct init; emit yz[t,e] = (y + u*D) * silu(z)
__global__ __launch_bounds__(256) void scan_pass3(
    const float* __restrict__ dt, const float* __restrict__ u,
    const float* __restrict__ dbc, const float* __restrict__ xz,
    const float* __restrict__ a_log, const float* __restrict__ Dp,
    const float* __restrict__ sInit, float* __restrict__ yz)
{
    const int tid = threadIdx.x;
    const int n = tid & 15, el = tid >> 4;
    const int e = blockIdx.x * 16 + el;
    const int c = blockIdx.y;
    const float Aen = -expf(a_log[e * NDIM + n]);
    const float dv = Dp[e];
    float s = sInit[((size_t)c * EDIM + e) * NDIM + n];
    const int t0 = c * CHLEN;
    for (int t = t0; t < t0 + CHLEN; t++) {
        float dtv = dt[(size_t)t * EDIM + e];
        float uv  = u[(size_t)t * EDIM + e];
        float Bv  = dbc[(size_t)t * 80 + RDIM + n];
        float Cv  = dbc[(size_t)t * 80 + RDIM + NDIM + n];
        s = s * expf(dtv * Aen) + dtv * Bv * uv;
        float p = s * Cv;
        p += __shfl_xor(p, 1, 16);
        p += __shfl_xor(p, 2, 16);
        p += __shfl_xor(p, 4, 16);
        p += __shfl_xor(p, 8, 16);
        if (n == 0) {
            float zv = xz[(size_t)t * (2 * EDIM) + EDIM + e];
            float y = p + uv * dv;
            yz[(size_t)t * EDIM + e] = y * siluf(zv);
        }
    }
}

extern "C" void kernel_launch(void* const* d_in, const int* in_sizes, int n_in,
                              void* d_out, int out_size, void* d_ws, size_t ws_size,
                              hipStream_t stream)
{
    const float* x        = (const float*)d_in[0];
    const float* emb_w    = (const float*)d_in[1];
    const float* emb_b    = (const float*)d_in[2];
    const float* norm_w   = (const float*)d_in[3];
    const float* in_proj  = (const float*)d_in[4];
    const float* conv_w   = (const float*)d_in[5];
    const float* conv_b   = (const float*)d_in[6];
    const float* x_proj   = (const float*)d_in[7];
    const float* dt_w     = (const float*)d_in[8];
    const float* dt_b     = (const float*)d_in[9];
    const float* A_log    = (const float*)d_in[10];
    const float* Dp       = (const float*)d_in[11];
    const float* out_proj = (const float*)d_in[12];
    const float* head_w   = (const float*)d_in[13];
    const float* head_b   = (const float*)d_in[14];
    float* out = (float*)d_out;

    float* ws = (float*)d_ws;
    size_t off = 0;
    float* h      = ws + off; off += (size_t)LSEQ * HDIM;
    float* res    = ws + off; off += (size_t)LSEQ * HDIM;
    float* hn     = ws + off; off += (size_t)LSEQ * HDIM;
    float* xz     = ws + off; off += (size_t)LSEQ * 2 * EDIM;
    float* u      = ws + off; off += (size_t)LSEQ * EDIM;
    float* dbc    = ws + off; off += (size_t)LSEQ * 80;
    float* dtb    = ws + off; off += (size_t)LSEQ * EDIM;
    float* yz     = ws + off; off += (size_t)LSEQ * EDIM;
    float* chunkS = ws + off; off += (size_t)NCHUNK * EDIM * NDIM;
    float* sumdt  = ws + off; off += (size_t)NCHUNK * EDIM;
    float* sInit  = ws + off; off += (size_t)NCHUNK * EDIM * NDIM;

    // 1. embed: h = x @ emb_w^T + emb_b   (M=1024, N=768, K=256)
    gemm_nt<true, false><<<dim3(HDIM / TS, LSEQ / TS), 256, 0, stream>>>(
        x, SDIM, emb_w, SDIM, emb_b, h, LSEQ, HDIM, SDIM);

    for (int i = 0; i < NLAYER; i++) {
        // 2a. residual + rmsnorm
        rmsnorm_res<<<LSEQ, 256, 0, stream>>>(h, res, hn, norm_w + (size_t)i * HDIM, i == 0);
        // 2b. in_proj: xz = hn @ in_w^T   (N=3072, K=768)
        gemm_nt<false, false><<<dim3(2 * EDIM / TS, LSEQ / TS), 256, 0, stream>>>(
            hn, HDIM, in_proj + (size_t)i * 2 * EDIM * HDIM, HDIM, nullptr, xz,
            LSEQ, 2 * EDIM, HDIM);
        // 2c. conv + silu
        conv_silu<<<dim3(EDIM / 256, LSEQ), 256, 0, stream>>>(
            xz, conv_w + (size_t)i * EDIM * KCONV, conv_b + (size_t)i * EDIM, u);
        // 2d. x_proj: dbc = u @ xp_w^T   (N=80, K=1536)
        gemm_nt<false, false><<<dim3((80 + TS - 1) / TS, LSEQ / TS), 256, 0, stream>>>(
            u, EDIM, x_proj + (size_t)i * 80 * EDIM, EDIM, nullptr, dbc,
            LSEQ, 80, EDIM);
        // 2e. dt = softplus(dbc[:, :48] @ dt_w^T + dt_b)   (N=1536, K=48, lda=80)
        gemm_nt<true, true><<<dim3(EDIM / TS, LSEQ / TS), 256, 0, stream>>>(
            dbc, 80, dt_w + (size_t)i * EDIM * RDIM, RDIM, dt_b + (size_t)i * EDIM, dtb,
            LSEQ, EDIM, RDIM);
        // 2f-h. selective scan (chunked)
        const float* al = A_log + (size_t)i * EDIM * NDIM;
        scan_pass1<<<dim3(EDIM / 16, NCHUNK), 256, 0, stream>>>(dtb, u, dbc, al, chunkS, sumdt);
        scan_pass2<<<EDIM * NDIM / 256, 256, 0, stream>>>(chunkS, sumdt, al, sInit);
        scan_pass3<<<dim3(EDIM / 16, NCHUNK), 256, 0, stream>>>(
            dtb, u, dbc, xz, al, Dp + (size_t)i * EDIM, sInit, yz);
        // 2i. out_proj: h = yz @ out_w^T   (N=768, K=1536)
        gemm_nt<false, false><<<dim3(HDIM / TS, LSEQ / TS), 256, 0, stream>>>(
            yz, EDIM, out_proj + (size_t)i * HDIM * EDIM, EDIM, nullptr, h,
            LSEQ, HDIM, EDIM);
    }

    // 3. head: out = h @ head_w^T + head_b  (N=256, K=768) -> fp32
    gemm_nt<true, false><<<dim3(SDIM / TS, LSEQ / TS), 256, 0, stream>>>(
        h, HDIM, head_w, HDIM, head_b, out, LSEQ, SDIM, HDIM);
}

// Round 3
// 620.912 us; speedup vs baseline: 2.3249x; 2.3249x over previous
//
#include <hip/hip_runtime.h>
#include <hip/hip_bf16.h>
#include <math.h>

// Problem dims
#define SDIM 256
#define HDIM 768
#define EDIM 1536
#define NDIM 16
#define KCONV 4
#define RDIM 48
#define NLAYER 2
#define LSEQ 1024

#define NCHUNK 16
#define CHLEN (LSEQ / NCHUNK)   // 64

typedef __hip_bfloat16 bf16;
typedef __attribute__((ext_vector_type(8))) short short8;   // 8 bf16 = 4 VGPRs
typedef __attribute__((ext_vector_type(4))) float f32x4;

__device__ __forceinline__ float softplusf(float x) {
    return (x > 20.f) ? x : log1pf(expf(x));
}
__device__ __forceinline__ float siluf(float x) {
    return x / (1.f + expf(-x));
}

// ---------------- fp32 -> bf16 convert ----------------
__global__ __launch_bounds__(256) void f2b(const float* __restrict__ in,
                                           bf16* __restrict__ out, int n)
{
    int i = (blockIdx.x * 256 + threadIdx.x) * 4;
    if (i + 3 < n) {
        float4 v = *(const float4*)(in + i);
        out[i + 0] = (bf16)v.x; out[i + 1] = (bf16)v.y;
        out[i + 2] = (bf16)v.z; out[i + 3] = (bf16)v.w;
    } else {
        for (int k = i; k < n; k++) out[k] = (bf16)in[k];
    }
}

// ---------------- MFMA bf16 GEMM: out[M,N] = A[M,K] @ W[N,K]^T ----------------
// M,N multiples of 64; K multiple of 64. A,W bf16; out fp32 (+ optional bf16 copy).
// 64x64 tile, 4 waves (2x2), each wave 32x32 via 2x2 of mfma_f32_16x16x32_bf16.
template<bool BIAS, bool OUTB>
__global__ __launch_bounds__(256) void gemm_mfma(
    const bf16* __restrict__ A, int lda,
    const bf16* __restrict__ W, int ldw,
    const float* __restrict__ bias,
    float* __restrict__ out, bf16* __restrict__ outb,
    int M, int N, int Kd)
{
    __shared__ __align__(16) short As[64][72];   // +8 pad: 2-way bank alias only
    __shared__ __align__(16) short Ws[64][72];

    const int tid  = threadIdx.x;
    const int lane = tid & 63;
    const int wid  = tid >> 6;
    const int wm   = wid >> 1, wn = wid & 1;      // 2x2 wave grid
    const int row0 = blockIdx.y * 64, col0 = blockIdx.x * 64;
    const int quad = lane >> 4;                   // 0..3
    const int l16  = lane & 15;

    f32x4 acc[2][2] = {};

    for (int k0 = 0; k0 < Kd; k0 += 64) {
        // stage A tile (64 rows x 64 k) and W tile (64 n x 64 k): 512 x 16B each
        #pragma unroll
        for (int i = 0; i < 2; i++) {
            int id = tid + i * 256;
            int r = id >> 3, g = id & 7;
            *(uint4*)&As[r][g * 8] =
                *(const uint4*)(A + (size_t)(row0 + r) * lda + k0 + g * 8);
            *(uint4*)&Ws[r][g * 8] =
                *(const uint4*)(W + (size_t)(col0 + r) * ldw + k0 + g * 8);
        }
        __syncthreads();
        #pragma unroll
        for (int ks = 0; ks < 64; ks += 32) {
            short8 af[2], bf[2];
            #pragma unroll
            for (int i = 0; i < 2; i++)
                af[i] = *(const short8*)&As[wm * 32 + i * 16 + l16][ks + quad * 8];
            #pragma unroll
            for (int j = 0; j < 2; j++)
                bf[j] = *(const short8*)&Ws[wn * 32 + j * 16 + l16][ks + quad * 8];
            #pragma unroll
            for (int i = 0; i < 2; i++)
                #pragma unroll
                for (int j = 0; j < 2; j++)
                    acc[i][j] = __builtin_amdgcn_mfma_f32_16x16x32_bf16(
                        af[i], bf[j], acc[i][j], 0, 0, 0);
        }
        __syncthreads();
    }

    // C layout: col = lane&15, row = quad*4 + reg
    #pragma unroll
    for (int i = 0; i < 2; i++) {
        #pragma unroll
        for (int j = 0; j < 2; j++) {
            int gn = col0 + wn * 32 + j * 16 + l16;
            int gm0 = row0 + wm * 32 + i * 16 + quad * 4;
            #pragma unroll
            for (int r = 0; r < 4; r++) {
                float v = acc[i][j][r];
                if (BIAS) v += bias[gn];
                size_t o = (size_t)(gm0 + r) * N + gn;
                out[o] = v;
                if (OUTB) outb[o] = (bf16)v;
            }
        }
    }
}

// ---------------- fp32 tiled NT GEMM (kept for dt_proj: K=48) ----------------
#define TS 64
#define KT 16

template<bool BIAS, bool SOFTPLUS>
__global__ __launch_bounds__(256) void gemm_nt_f32(
    const float* __restrict__ A, int lda,
    const float* __restrict__ W, int ldw,
    const float* __restrict__ bias,
    float* __restrict__ out, int M, int N, int Kd)
{
    __shared__ float As[KT][TS + 4];
    __shared__ float Ws[KT][TS + 4];
    const int tid = threadIdx.x;
    const int tx = tid & 15, ty = tid >> 4;
    const int tx4 = tx * 4, ty4 = ty * 4;
    const int row0 = blockIdx.y * TS, col0 = blockIdx.x * TS;

    float acc[4][4] = {};

    for (int k0 = 0; k0 < Kd; k0 += KT) {
        #pragma unroll
        for (int i = 0; i < 4; i++) {
            int idx = tid + i * 256;
            int m = idx >> 4, kk = idx & 15;
            int gm = row0 + m, gk = k0 + kk;
            float v = 0.f;
            if (gm < M && gk < Kd) v = A[(size_t)gm * lda + gk];
            As[kk][m] = v;
        }
        #pragma unroll
        for (int i = 0; i < 4; i++) {
            int idx = tid + i * 256;
            int nn = idx >> 4, kk = idx & 15;
            int gn = col0 + nn, gk = k0 + kk;
            float v = 0.f;
            if (gn < N && gk < Kd) v = W[(size_t)gn * ldw + gk];
            Ws[kk][nn] = v;
        }
        __syncthreads();
        #pragma unroll
        for (int kk = 0; kk < KT; kk++) {
            float a[4], b[4];
            #pragma unroll
            for (int i = 0; i < 4; i++) a[i] = As[kk][ty4 + i];
            #pragma unroll
            for (int j = 0; j < 4; j++) b[j] = Ws[kk][tx4 + j];
            #pragma unroll
            for (int i = 0; i < 4; i++)
                #pragma unroll
                for (int j = 0; j < 4; j++)
                    acc[i][j] += a[i] * b[j];
        }
        __syncthreads();
    }

    #pragma unroll
    for (int i = 0; i < 4; i++) {
        int gm = row0 + ty4 + i;
        if (gm >= M) continue;
        #pragma unroll
        for (int j = 0; j < 4; j++) {
            int gn = col0 + tx4 + j;
            if (gn >= N) continue;
            float v = acc[i][j];
            if (BIAS) v += bias[gn];
            if (SOFTPLUS) v = softplusf(v);
            out[(size_t)gm * N + gn] = v;
        }
    }
}

// ---------------- x_proj split-K: part[s][t][j] = u[t, s*384:+384] . xw[j, ...] ----------------
#define KSPLIT 4
#define KCH (EDIM / KSPLIT)   // 384

__global__ __launch_bounds__(256) void xproj_partial(
    const float* __restrict__ u, const float* __restrict__ xw,
    float* __restrict__ part)
{
    int idx = blockIdx.x * 256 + threadIdx.x;     // (s, t, j)
    int j = idx % 80;
    int r = idx / 80;
    int t = r & (LSEQ - 1);
    int s = r >> 10;
    const float4* u4 = (const float4*)(u + (size_t)t * EDIM + s * KCH);
    const float4* w4 = (const float4*)(xw + (size_t)j * EDIM + s * KCH);
    float acc = 0.f;
    #pragma unroll 4
    for (int k = 0; k < KCH / 4; k++) {
        float4 a = u4[k], b = w4[k];
        acc += a.x * b.x + a.y * b.y + a.z * b.z + a.w * b.w;
    }
    part[(size_t)s * (LSEQ * 80) + (size_t)t * 80 + j] = acc;
}

__global__ __launch_bounds__(256) void reduce_dbc(
    const float* __restrict__ part, float* __restrict__ dbc)
{
    int idx = blockIdx.x * 256 + threadIdx.x;     // 0 .. 1024*80-1
    float s = 0.f;
    #pragma unroll
    for (int k = 0; k < KSPLIT; k++) s += part[(size_t)k * (LSEQ * 80) + idx];
    dbc[idx] = s;
}

// ---------------- Residual add + RMSNorm -> bf16 ----------------
__global__ __launch_bounds__(256) void rmsnorm_res(
    const float* __restrict__ h, float* __restrict__ res, bf16* __restrict__ hnb,
    const float* __restrict__ w, int first)
{
    const int t = blockIdx.x;
    const int tid = threadIdx.x;
    float v[3];
    float ss = 0.f;
    #pragma unroll
    for (int r = 0; r < 3; r++) {
        int j = tid + r * 256;
        float x = h[(size_t)t * HDIM + j];
        if (!first) x += res[(size_t)t * HDIM + j];
        v[r] = x;
        res[(size_t)t * HDIM + j] = x;
        ss += x * x;
    }
    #pragma unroll
    for (int m = 32; m >= 1; m >>= 1) ss += __shfl_down(ss, m);
    __shared__ float red[4];
    int wid = tid >> 6;
    if ((tid & 63) == 0) red[wid] = ss;
    __syncthreads();
    __shared__ float stot;
    if (tid == 0) stot = red[0] + red[1] + red[2] + red[3];
    __syncthreads();
    float scale = rsqrtf(stot / (float)HDIM + 1e-5f);
    #pragma unroll
    for (int r = 0; r < 3; r++) {
        int j = tid + r * 256;
        hnb[(size_t)t * HDIM + j] = (bf16)(v[r] * scale * w[j]);
    }
}

// ---------------- Depthwise causal conv1d + SiLU ----------------
__global__ __launch_bounds__(256) void conv_silu(
    const float* __restrict__ xz, const float* __restrict__ cw,
    const float* __restrict__ cb, float* __restrict__ u)
{
    const int e = blockIdx.x * 256 + threadIdx.x;
    const int t = blockIdx.y;
    float s = cb[e];
    #pragma unroll
    for (int k = 0; k < KCONV; k++) {
        int tt = t - (KCONV - 1) + k;
        if (tt >= 0) s += cw[e * KCONV + k] * xz[(size_t)tt * (2 * EDIM) + e];
    }
    u[(size_t)t * EDIM + e] = siluf(s);
}

// ---------------- Selective scan, chunked ----------------
__global__ __launch_bounds__(256) void scan_pass1(
    const float* __restrict__ dt, const float* __restrict__ u,
    const float* __restrict__ dbc, const float* __restrict__ a_log,
    float* __restrict__ chunkS, float* __restrict__ sumdt)
{
    const int tid = threadIdx.x;
    const int n = tid & 15, el = tid >> 4;
    const int e = blockIdx.x * 16 + el;
    const int c = blockIdx.y;
    const float Aen = -expf(a_log[e * NDIM + n]);
    float s = 0.f, sd = 0.f;
    const int t0 = c * CHLEN;
    for (int t = t0; t < t0 + CHLEN; t++) {
        float dtv = dt[(size_t)t * EDIM + e];
        float uv  = u[(size_t)t * EDIM + e];
        float Bv  = dbc[(size_t)t * 80 + RDIM + n];
        s = s * expf(dtv * Aen) + dtv * Bv * uv;
        sd += dtv;
    }
    chunkS[((size_t)c * EDIM + e) * NDIM + n] = s;
    if (n == 0) sumdt[(size_t)c * EDIM + e] = sd;
}

__global__ __launch_bounds__(256) void scan_pass2(
    const float* __restrict__ chunkS, const float* __restrict__ sumdt,
    const float* __restrict__ a_log, float* __restrict__ sInit)
{
    const int idx = blockIdx.x * 256 + threadIdx.x;  // 0..E*N-1
    const int n = idx & 15, e = idx >> 4;
    const float Aen = -expf(a_log[idx]);
    float s = 0.f;
    for (int c = 0; c < NCHUNK; c++) {
        sInit[((size_t)c * EDIM + e) * NDIM + n] = s;
        float P = expf(Aen * sumdt[(size_t)c * EDIM + e]);
        s = s * P + chunkS[((size_t)c * EDIM + e) * NDIM + n];
    }
}

__global__ __launch_bounds__(256) void scan_pass3(
    const float* __restrict__ dt, const float* __restrict__ u,
    const float* __restrict__ dbc, const float* __restrict__ xz,
    const float* __restrict__ a_log, const float* __restrict__ Dp,
    const float* __restrict__ sInit, bf16* __restrict__ yzb)
{
    const int tid = threadIdx.x;
    const int n = tid & 15, el = tid >> 4;
    const int e = blockIdx.x * 16 + el;
    const int c = blockIdx.y;
    const float Aen = -expf(a_log[e * NDIM + n]);
    const float dv = Dp[e];
    float s = sInit[((size_t)c * EDIM + e) * NDIM + n];
    const int t0 = c * CHLEN;
    for (int t = t0; t < t0 + CHLEN; t++) {
        float dtv = dt[(size_t)t * EDIM + e];
        float uv  = u[(size_t)t * EDIM + e];
        float Bv  = dbc[(size_t)t * 80 + RDIM + n];
        float Cv  = dbc[(size_t)t * 80 + RDIM + NDIM + n];
        s = s * expf(dtv * Aen) + dtv * Bv * uv;
        float p = s * Cv;
        p += __shfl_xor(p, 1, 16);
        p += __shfl_xor(p, 2, 16);
        p += __shfl_xor(p, 4, 16);
        p += __shfl_xor(p, 8, 16);
        if (n == 0) {
            float zv = xz[(size_t)t * (2 * EDIM) + EDIM + e];
            float y = p + uv * dv;
            yzb[(size_t)t * EDIM + e] = (bf16)(y * siluf(zv));
        }
    }
}

extern "C" void kernel_launch(void* const* d_in, const int* in_sizes, int n_in,
                              void* d_out, int out_size, void* d_ws, size_t ws_size,
                              hipStream_t stream)
{
    const float* x        = (const float*)d_in[0];
    const float* emb_w    = (const float*)d_in[1];
    const float* emb_b    = (const float*)d_in[2];
    const float* norm_w   = (const float*)d_in[3];
    const float* in_proj  = (const float*)d_in[4];
    const float* conv_w   = (const float*)d_in[5];
    const float* conv_b   = (const float*)d_in[6];
    const float* x_proj   = (const float*)d_in[7];
    const float* dt_w     = (const float*)d_in[8];
    const float* dt_b     = (const float*)d_in[9];
    const float* A_log    = (const float*)d_in[10];
    const float* Dp       = (const float*)d_in[11];
    const float* out_proj = (const float*)d_in[12];
    const float* head_w   = (const float*)d_in[13];
    const float* head_b   = (const float*)d_in[14];
    float* out = (float*)d_out;

    float* ws = (float*)d_ws;
    size_t off = 0;
    float* h      = ws + off; off += (size_t)LSEQ * HDIM;
    float* res    = ws + off; off += (size_t)LSEQ * HDIM;
    float* xz     = ws + off; off += (size_t)LSEQ * 2 * EDIM;
    float* u      = ws + off; off += (size_t)LSEQ * EDIM;
    float* dbc    = ws + off; off += (size_t)LSEQ * 80;
    float* part   = ws + off; off += (size_t)KSPLIT * LSEQ * 80;
    float* dtb    = ws + off; off += (size_t)LSEQ * EDIM;
    float* chunkS = ws + off; off += (size_t)NCHUNK * EDIM * NDIM;
    float* sumdt  = ws + off; off += (size_t)NCHUNK * EDIM;
    float* sInit  = ws + off; off += (size_t)NCHUNK * EDIM * NDIM;
    // bf16 buffers (2 bytes) — carve from remaining fp32 words
    bf16* hnb     = (bf16*)(ws + off); off += (size_t)LSEQ * HDIM / 2;
    bf16* yzb     = (bf16*)(ws + off); off += (size_t)LSEQ * EDIM / 2;
    bf16* hb      = (bf16*)(ws + off); off += (size_t)LSEQ * HDIM / 2;
    bf16* xb      = (bf16*)(ws + off); off += (size_t)LSEQ * SDIM / 2;
    bf16* emb_wb  = (bf16*)(ws + off); off += (size_t)HDIM * SDIM / 2;
    bf16* head_wb = (bf16*)(ws + off); off += (size_t)SDIM * HDIM / 2;
    bf16* in_wb   = (bf16*)(ws + off); off += (size_t)2 * EDIM * HDIM / 2;
    bf16* out_wb  = (bf16*)(ws + off); off += (size_t)HDIM * EDIM / 2;

    // weight / input conversions (layer-invariant)
    f2b<<<(LSEQ * SDIM / 4 + 255) / 256, 256, 0, stream>>>(x, xb, LSEQ * SDIM);
    f2b<<<(HDIM * SDIM / 4 + 255) / 256, 256, 0, stream>>>(emb_w, emb_wb, HDIM * SDIM);
    f2b<<<(SDIM * HDIM / 4 + 255) / 256, 256, 0, stream>>>(head_w, head_wb, SDIM * HDIM);

    // 1. embed: h = x @ emb_w^T + emb_b   (M=1024, N=768, K=256)
    gemm_mfma<true, false><<<dim3(HDIM / 64, LSEQ / 64), 256, 0, stream>>>(
        xb, SDIM, emb_wb, SDIM, emb_b, h, nullptr, LSEQ, HDIM, SDIM);

    for (int i = 0; i < NLAYER; i++) {
        f2b<<<(2 * EDIM * HDIM / 4 + 255) / 256, 256, 0, stream>>>(
            in_proj + (size_t)i * 2 * EDIM * HDIM, in_wb, 2 * EDIM * HDIM);
        f2b<<<(HDIM * EDIM / 4 + 255) / 256, 256, 0, stream>>>(
            out_proj + (size_t)i * HDIM * EDIM, out_wb, HDIM * EDIM);

        // 2a. residual + rmsnorm -> bf16
        rmsnorm_res<<<LSEQ, 256, 0, stream>>>(h, res, hnb, norm_w + (size_t)i * HDIM, i == 0);
        // 2b. in_proj: xz = hn @ in_w^T   (N=3072, K=768)
        gemm_mfma<false, false><<<dim3(2 * EDIM / 64, LSEQ / 64), 256, 0, stream>>>(
            hnb, HDIM, in_wb, HDIM, nullptr, xz, nullptr, LSEQ, 2 * EDIM, HDIM);
        // 2c. conv + silu
        conv_silu<<<dim3(EDIM / 256, LSEQ), 256, 0, stream>>>(
            xz, conv_w + (size_t)i * EDIM * KCONV, conv_b + (size_t)i * EDIM, u);
        // 2d. x_proj split-K: dbc = u @ xp_w^T   (N=80, K=1536)
        xproj_partial<<<KSPLIT * LSEQ * 80 / 256, 256, 0, stream>>>(
            u, x_proj + (size_t)i * 80 * EDIM, part);
        reduce_dbc<<<LSEQ * 80 / 256, 256, 0, stream>>>(part, dbc);
        // 2e. dt = softplus(dbc[:, :48] @ dt_w^T + dt_b)
        gemm_nt_f32<true, true><<<dim3(EDIM / TS, LSEQ / TS), 256, 0, stream>>>(
            dbc, 80, dt_w + (size_t)i * EDIM * RDIM, RDIM, dt_b + (size_t)i * EDIM, dtb,
            LSEQ, EDIM, RDIM);
        // 2f-h. selective scan (chunked)
        const float* al = A_log + (size_t)i * EDIM * NDIM;
        scan_pass1<<<dim3(EDIM / 16, NCHUNK), 256, 0, stream>>>(dtb, u, dbc, al, chunkS, sumdt);
        scan_pass2<<<EDIM * NDIM / 256, 256, 0, stream>>>(chunkS, sumdt, al, sInit);
        scan_pass3<<<dim3(EDIM / 16, NCHUNK), 256, 0, stream>>>(
            dtb, u, dbc, xz, al, Dp + (size_t)i * EDIM, sInit, yzb);
        // 2i. out_proj: h = yz @ out_w^T   (N=768, K=1536); last layer also bf16 copy
        if (i == NLAYER - 1)
            gemm_mfma<false, true><<<dim3(HDIM / 64, LSEQ / 64), 256, 0, stream>>>(
                yzb, EDIM, out_wb, EDIM, nullptr, h, hb, LSEQ, HDIM, EDIM);
        else
            gemm_mfma<false, false><<<dim3(HDIM / 64, LSEQ / 64), 256, 0, stream>>>(
                yzb, EDIM, out_wb, EDIM, nullptr, h, nullptr, LSEQ, HDIM, EDIM);
    }

    // 3. head: out = h @ head_w^T + head_b  (N=256, K=768)
    gemm_mfma<true, false><<<dim3(SDIM / 64, LSEQ / 64), 256, 0, stream>>>(
        hb, HDIM, head_wb, HDIM, head_b, out, nullptr, LSEQ, SDIM, HDIM);
}

// Round 5
// 525.007 us; speedup vs baseline: 2.7496x; 1.1827x over previous
//
#include <hip/hip_runtime.h>
#include <hip/hip_bf16.h>
#include <math.h>

// Problem dims
#define SDIM 256
#define HDIM 768
#define EDIM 1536
#define NDIM 16
#define KCONV 4
#define RDIM 48
#define NLAYER 2
#define LSEQ 1024

#define NCHUNK 16
#define CHLEN (LSEQ / NCHUNK)   // 64

typedef __hip_bfloat16 bf16;
typedef __attribute__((ext_vector_type(8))) short short8;   // 8 bf16 = 4 VGPRs
typedef __attribute__((ext_vector_type(4))) float f32x4;

__device__ __forceinline__ float softplusf(float x) {
    return (x > 20.f) ? x : log1pf(expf(x));
}
__device__ __forceinline__ float siluf(float x) {
    return x / (1.f + expf(-x));
}

// ---------------- fp32 -> bf16 convert ----------------
__global__ __launch_bounds__(256) void f2b(const float* __restrict__ in,
                                           bf16* __restrict__ out, int n)
{
    int i = (blockIdx.x * 256 + threadIdx.x) * 4;
    if (i + 3 < n) {
        float4 v = *(const float4*)(in + i);
        out[i + 0] = (bf16)v.x; out[i + 1] = (bf16)v.y;
        out[i + 2] = (bf16)v.z; out[i + 3] = (bf16)v.w;
    } else {
        for (int k = i; k < n; k++) out[k] = (bf16)in[k];
    }
}

// ---------------- MFMA bf16 GEMM: out[M,N] = A[M,K] @ W[N,K]^T ----------------
// M,N multiples of 64; K multiple of 64. A,W bf16; out fp32 (+ optional bf16 copy).
// 64x64 tile, 4 waves (2x2), each wave 32x32 via 2x2 of mfma_f32_16x16x32_bf16.
template<bool BIAS, bool OUTB>
__global__ __launch_bounds__(256) void gemm_mfma(
    const bf16* __restrict__ A, int lda,
    const bf16* __restrict__ W, int ldw,
    const float* __restrict__ bias,
    float* __restrict__ out, bf16* __restrict__ outb,
    int M, int N, int Kd)
{
    __shared__ __align__(16) short As[64][72];   // +8 pad: 2-way bank alias only
    __shared__ __align__(16) short Ws[64][72];

    const int tid  = threadIdx.x;
    const int lane = tid & 63;
    const int wid  = tid >> 6;
    const int wm   = wid >> 1, wn = wid & 1;      // 2x2 wave grid
    const int row0 = blockIdx.y * 64, col0 = blockIdx.x * 64;
    const int quad = lane >> 4;                   // 0..3
    const int l16  = lane & 15;

    f32x4 acc[2][2] = {};

    for (int k0 = 0; k0 < Kd; k0 += 64) {
        #pragma unroll
        for (int i = 0; i < 2; i++) {
            int id = tid + i * 256;
            int r = id >> 3, g = id & 7;
            *(uint4*)&As[r][g * 8] =
                *(const uint4*)(A + (size_t)(row0 + r) * lda + k0 + g * 8);
            *(uint4*)&Ws[r][g * 8] =
                *(const uint4*)(W + (size_t)(col0 + r) * ldw + k0 + g * 8);
        }
        __syncthreads();
        #pragma unroll
        for (int ks = 0; ks < 64; ks += 32) {
            short8 af[2], bf[2];
            #pragma unroll
            for (int i = 0; i < 2; i++)
                af[i] = *(const short8*)&As[wm * 32 + i * 16 + l16][ks + quad * 8];
            #pragma unroll
            for (int j = 0; j < 2; j++)
                bf[j] = *(const short8*)&Ws[wn * 32 + j * 16 + l16][ks + quad * 8];
            #pragma unroll
            for (int i = 0; i < 2; i++)
                #pragma unroll
                for (int j = 0; j < 2; j++)
                    acc[i][j] = __builtin_amdgcn_mfma_f32_16x16x32_bf16(
                        af[i], bf[j], acc[i][j], 0, 0, 0);
        }
        __syncthreads();
    }

    // C layout: col = lane&15, row = quad*4 + reg
    #pragma unroll
    for (int i = 0; i < 2; i++) {
        #pragma unroll
        for (int j = 0; j < 2; j++) {
            int gn = col0 + wn * 32 + j * 16 + l16;
            int gm0 = row0 + wm * 32 + i * 16 + quad * 4;
            #pragma unroll
            for (int r = 0; r < 4; r++) {
                float v = acc[i][j][r];
                if (BIAS) v += bias[gn];
                size_t o = (size_t)(gm0 + r) * N + gn;
                out[o] = v;
                if (OUTB) outb[o] = (bf16)v;
            }
        }
    }
}

// ---------------- fp32 tiled NT GEMM (dt_proj: K=48) ----------------
#define TS 64
#define KT 16

template<bool BIAS, bool SOFTPLUS>
__global__ __launch_bounds__(256) void gemm_nt_f32(
    const float* __restrict__ A, int lda,
    const float* __restrict__ W, int ldw,
    const float* __restrict__ bias,
    float* __restrict__ out, int M, int N, int Kd)
{
    __shared__ float As[KT][TS + 4];
    __shared__ float Ws[KT][TS + 4];
    const int tid = threadIdx.x;
    const int tx = tid & 15, ty = tid >> 4;
    const int tx4 = tx * 4, ty4 = ty * 4;
    const int row0 = blockIdx.y * TS, col0 = blockIdx.x * TS;

    float acc[4][4] = {};

    for (int k0 = 0; k0 < Kd; k0 += KT) {
        #pragma unroll
        for (int i = 0; i < 4; i++) {
            int idx = tid + i * 256;
            int m = idx >> 4, kk = idx & 15;
            int gm = row0 + m, gk = k0 + kk;
            float v = 0.f;
            if (gm < M && gk < Kd) v = A[(size_t)gm * lda + gk];
            As[kk][m] = v;
        }
        #pragma unroll
        for (int i = 0; i < 4; i++) {
            int idx = tid + i * 256;
            int nn = idx >> 4, kk = idx & 15;
            int gn = col0 + nn, gk = k0 + kk;
            float v = 0.f;
            if (gn < N && gk < Kd) v = W[(size_t)gn * ldw + gk];
            Ws[kk][nn] = v;
        }
        __syncthreads();
        #pragma unroll
        for (int kk = 0; kk < KT; kk++) {
            float a[4], b[4];
            #pragma unroll
            for (int i = 0; i < 4; i++) a[i] = As[kk][ty4 + i];
            #pragma unroll
            for (int j = 0; j < 4; j++) b[j] = Ws[kk][tx4 + j];
            #pragma unroll
            for (int i = 0; i < 4; i++)
                #pragma unroll
                for (int j = 0; j < 4; j++)
                    acc[i][j] += a[i] * b[j];
        }
        __syncthreads();
    }

    #pragma unroll
    for (int i = 0; i < 4; i++) {
        int gm = row0 + ty4 + i;
        if (gm >= M) continue;
        #pragma unroll
        for (int j = 0; j < 4; j++) {
            int gn = col0 + tx4 + j;
            if (gn >= N) continue;
            float v = acc[i][j];
            if (BIAS) v += bias[gn];
            if (SOFTPLUS) v = softplusf(v);
            out[(size_t)gm * N + gn] = v;
        }
    }
}

// ---------------- x_proj: split-K LDS-tiled fp32 GEMM ----------------
// part[s][t][j] partial over K-chunk s; grid (2, 16, KSPLIT); N=80 bounds-checked.
#define KSPLIT 8
#define KCH (EDIM / KSPLIT)   // 192

__global__ __launch_bounds__(256) void xproj_gemm(
    const float* __restrict__ u, const float* __restrict__ xw,
    float* __restrict__ part)
{
    __shared__ float As[KT][TS + 4];
    __shared__ float Ws[KT][TS + 4];
    const int tid = threadIdx.x;
    const int tx = tid & 15, ty = tid >> 4;
    const int tx4 = tx * 4, ty4 = ty * 4;
    const int row0 = blockIdx.y * TS, col0 = blockIdx.x * TS;
    const int kbase = blockIdx.z * KCH;

    float acc[4][4] = {};

    for (int k0 = 0; k0 < KCH; k0 += KT) {
        #pragma unroll
        for (int i = 0; i < 4; i++) {
            int idx = tid + i * 256;
            int m = idx >> 4, kk = idx & 15;
            As[kk][m] = u[(size_t)(row0 + m) * EDIM + kbase + k0 + kk];
        }
        #pragma unroll
        for (int i = 0; i < 4; i++) {
            int idx = tid + i * 256;
            int nn = idx >> 4, kk = idx & 15;
            int gn = col0 + nn;
            float v = 0.f;
            if (gn < 80) v = xw[(size_t)gn * EDIM + kbase + k0 + kk];
            Ws[kk][nn] = v;
        }
        __syncthreads();
        #pragma unroll
        for (int kk = 0; kk < KT; kk++) {
            float a[4], b[4];
            #pragma unroll
            for (int i = 0; i < 4; i++) a[i] = As[kk][ty4 + i];
            #pragma unroll
            for (int j = 0; j < 4; j++) b[j] = Ws[kk][tx4 + j];
            #pragma unroll
            for (int i = 0; i < 4; i++)
                #pragma unroll
                for (int j = 0; j < 4; j++)
                    acc[i][j] += a[i] * b[j];
        }
        __syncthreads();
    }

    float* pdst = part + (size_t)blockIdx.z * (LSEQ * 80);
    #pragma unroll
    for (int i = 0; i < 4; i++) {
        int gm = row0 + ty4 + i;
        #pragma unroll
        for (int j = 0; j < 4; j++) {
            int gn = col0 + tx4 + j;
            if (gn < 80) pdst[(size_t)gm * 80 + gn] = acc[i][j];
        }
    }
}

__global__ __launch_bounds__(256) void reduce_dbc(
    const float* __restrict__ part, float* __restrict__ dbc)
{
    int idx = blockIdx.x * 256 + threadIdx.x;     // 0 .. 1024*80-1
    float s = 0.f;
    #pragma unroll
    for (int k = 0; k < KSPLIT; k++) s += part[(size_t)k * (LSEQ * 80) + idx];
    dbc[idx] = s;
}

// ---------------- Residual add + RMSNorm -> bf16 ----------------
__global__ __launch_bounds__(256) void rmsnorm_res(
    const float* __restrict__ h, float* __restrict__ res, bf16* __restrict__ hnb,
    const float* __restrict__ w, int first)
{
    const int t = blockIdx.x;
    const int tid = threadIdx.x;
    float v[3];
    float ss = 0.f;
    #pragma unroll
    for (int r = 0; r < 3; r++) {
        int j = tid + r * 256;
        float x = h[(size_t)t * HDIM + j];
        if (!first) x += res[(size_t)t * HDIM + j];
        v[r] = x;
        res[(size_t)t * HDIM + j] = x;
        ss += x * x;
    }
    #pragma unroll
    for (int m = 32; m >= 1; m >>= 1) ss += __shfl_down(ss, m);
    __shared__ float red[4];
    int wid = tid >> 6;
    if ((tid & 63) == 0) red[wid] = ss;
    __syncthreads();
    __shared__ float stot;
    if (tid == 0) stot = red[0] + red[1] + red[2] + red[3];
    __syncthreads();
    float scale = rsqrtf(stot / (float)HDIM + 1e-5f);
    #pragma unroll
    for (int r = 0; r < 3; r++) {
        int j = tid + r * 256;
        hnb[(size_t)t * HDIM + j] = (bf16)(v[r] * scale * w[j]);
    }
}

// ---------------- Depthwise causal conv1d + SiLU ----------------
__global__ __launch_bounds__(256) void conv_silu(
    const float* __restrict__ xz, const float* __restrict__ cw,
    const float* __restrict__ cb, float* __restrict__ u)
{
    const int e = blockIdx.x * 256 + threadIdx.x;
    const int t = blockIdx.y;
    float s = cb[e];
    #pragma unroll
    for (int k = 0; k < KCONV; k++) {
        int tt = t - (KCONV - 1) + k;
        if (tt >= 0) s += cw[e * KCONV + k] * xz[(size_t)tt * (2 * EDIM) + e];
    }
    u[(size_t)t * EDIM + e] = siluf(s);
}

// ---------------- Selective scan, chunked ----------------
__global__ __launch_bounds__(256) void scan_pass1(
    const float* __restrict__ dt, const float* __restrict__ u,
    const float* __restrict__ dbc, const float* __restrict__ a_log,
    float* __restrict__ chunkS, float* __restrict__ sumdt)
{
    const int tid = threadIdx.x;
    const int n = tid & 15, el = tid >> 4;
    const int e = blockIdx.x * 16 + el;
    const int c = blockIdx.y;
    const float Aen = -expf(a_log[e * NDIM + n]);
    float s = 0.f, sd = 0.f;
    const int t0 = c * CHLEN;
    for (int t = t0; t < t0 + CHLEN; t++) {
        float dtv = dt[(size_t)t * EDIM + e];
        float uv  = u[(size_t)t * EDIM + e];
        float Bv  = dbc[(size_t)t * 80 + RDIM + n];
        s = s * expf(dtv * Aen) + dtv * Bv * uv;
        sd += dtv;
    }
    chunkS[((size_t)c * EDIM + e) * NDIM + n] = s;
    if (n == 0) sumdt[(size_t)c * EDIM + e] = sd;
}

__global__ __launch_bounds__(256) void scan_pass2(
    const float* __restrict__ chunkS, const float* __restrict__ sumdt,
    const float* __restrict__ a_log, float* __restrict__ sInit)
{
    const int idx = blockIdx.x * 256 + threadIdx.x;  // 0..E*N-1
    const int n = idx & 15, e = idx >> 4;
    const float Aen = -expf(a_log[idx]);
    float s = 0.f;
    for (int c = 0; c < NCHUNK; c++) {
        sInit[((size_t)c * EDIM + e) * NDIM + n] = s;
        float P = expf(Aen * sumdt[(size_t)c * EDIM + e]);
        s = s * P + chunkS[((size_t)c * EDIM + e) * NDIM + n];
    }
}

__global__ __launch_bounds__(256) void scan_pass3(
    const float* __restrict__ dt, const float* __restrict__ u,
    const float* __restrict__ dbc, const float* __restrict__ xz,
    const float* __restrict__ a_log, const float* __restrict__ Dp,
    const float* __restrict__ sInit, bf16* __restrict__ yzb)
{
    const int tid = threadIdx.x;
    const int n = tid & 15, el = tid >> 4;
    const int e = blockIdx.x * 16 + el;
    const int c = blockIdx.y;
    const float Aen = -expf(a_log[e * NDIM + n]);
    const float dv = Dp[e];
    float s = sInit[((size_t)c * EDIM + e) * NDIM + n];
    const int t0 = c * CHLEN;
    for (int t = t0; t < t0 + CHLEN; t++) {
        float dtv = dt[(size_t)t * EDIM + e];
        float uv  = u[(size_t)t * EDIM + e];
        float Bv  = dbc[(size_t)t * 80 + RDIM + n];
        float Cv  = dbc[(size_t)t * 80 + RDIM + NDIM + n];
        s = s * expf(dtv * Aen) + dtv * Bv * uv;
        float p = s * Cv;
        p += __shfl_xor(p, 1, 16);
        p += __shfl_xor(p, 2, 16);
        p += __shfl_xor(p, 4, 16);
        p += __shfl_xor(p, 8, 16);
        if (n == 0) {
            float zv = xz[(size_t)t * (2 * EDIM) + EDIM + e];
            float y = p + uv * dv;
            yzb[(size_t)t * EDIM + e] = (bf16)(y * siluf(zv));
        }
    }
}

extern "C" void kernel_launch(void* const* d_in, const int* in_sizes, int n_in,
                              void* d_out, int out_size, void* d_ws, size_t ws_size,
                              hipStream_t stream)
{
    const float* x        = (const float*)d_in[0];
    const float* emb_w    = (const float*)d_in[1];
    const float* emb_b    = (const float*)d_in[2];
    const float* norm_w   = (const float*)d_in[3];
    const float* in_proj  = (const float*)d_in[4];
    const float* conv_w   = (const float*)d_in[5];
    const float* conv_b   = (const float*)d_in[6];
    const float* x_proj   = (const float*)d_in[7];
    const float* dt_w     = (const float*)d_in[8];
    const float* dt_b     = (const float*)d_in[9];
    const float* A_log    = (const float*)d_in[10];
    const float* Dp       = (const float*)d_in[11];
    const float* out_proj = (const float*)d_in[12];
    const float* head_w   = (const float*)d_in[13];
    const float* head_b   = (const float*)d_in[14];
    float* out = (float*)d_out;

    float* ws = (float*)d_ws;
    size_t off = 0;
    float* h      = ws + off; off += (size_t)LSEQ * HDIM;
    float* res    = ws + off; off += (size_t)LSEQ * HDIM;
    float* xz     = ws + off; off += (size_t)LSEQ * 2 * EDIM;
    float* u      = ws + off; off += (size_t)LSEQ * EDIM;
    float* dbc    = ws + off; off += (size_t)LSEQ * 80;
    float* part   = ws + off; off += (size_t)KSPLIT * LSEQ * 80;
    float* dtb    = ws + off; off += (size_t)LSEQ * EDIM;
    float* chunkS = ws + off; off += (size_t)NCHUNK * EDIM * NDIM;
    float* sumdt  = ws + off; off += (size_t)NCHUNK * EDIM;
    float* sInit  = ws + off; off += (size_t)NCHUNK * EDIM * NDIM;
    // bf16 buffers (2 bytes) — carve from remaining fp32 words
    bf16* hnb     = (bf16*)(ws + off); off += (size_t)LSEQ * HDIM / 2;
    bf16* yzb     = (bf16*)(ws + off); off += (size_t)LSEQ * EDIM / 2;
    bf16* hb      = (bf16*)(ws + off); off += (size_t)LSEQ * HDIM / 2;
    bf16* xb      = (bf16*)(ws + off); off += (size_t)LSEQ * SDIM / 2;
    bf16* emb_wb  = (bf16*)(ws + off); off += (size_t)HDIM * SDIM / 2;
    bf16* head_wb = (bf16*)(ws + off); off += (size_t)SDIM * HDIM / 2;
    bf16* in_wb   = (bf16*)(ws + off); off += (size_t)2 * EDIM * HDIM / 2;
    bf16* out_wb  = (bf16*)(ws + off); off += (size_t)HDIM * EDIM / 2;

    // weight / input conversions (layer-invariant)
    f2b<<<(LSEQ * SDIM / 4 + 255) / 256, 256, 0, stream>>>(x, xb, LSEQ * SDIM);
    f2b<<<(HDIM * SDIM / 4 + 255) / 256, 256, 0, stream>>>(emb_w, emb_wb, HDIM * SDIM);
    f2b<<<(SDIM * HDIM / 4 + 255) / 256, 256, 0, stream>>>(head_w, head_wb, SDIM * HDIM);

    // 1. embed: h = x @ emb_w^T + emb_b   (M=1024, N=768, K=256)
    gemm_mfma<true, false><<<dim3(HDIM / 64, LSEQ / 64), 256, 0, stream>>>(
        xb, SDIM, emb_wb, SDIM, emb_b, h, nullptr, LSEQ, HDIM, SDIM);

    for (int i = 0; i < NLAYER; i++) {
        f2b<<<(2 * EDIM * HDIM / 4 + 255) / 256, 256, 0, stream>>>(
            in_proj + (size_t)i * 2 * EDIM * HDIM, in_wb, 2 * EDIM * HDIM);
        f2b<<<(HDIM * EDIM / 4 + 255) / 256, 256, 0, stream>>>(
            out_proj + (size_t)i * HDIM * EDIM, out_wb, HDIM * EDIM);

        // 2a. residual + rmsnorm -> bf16
        rmsnorm_res<<<LSEQ, 256, 0, stream>>>(h, res, hnb, norm_w + (size_t)i * HDIM, i == 0);
        // 2b. in_proj: xz = hn @ in_w^T   (N=3072, K=768)
        gemm_mfma<false, false><<<dim3(2 * EDIM / 64, LSEQ / 64), 256, 0, stream>>>(
            hnb, HDIM, in_wb, HDIM, nullptr, xz, nullptr, LSEQ, 2 * EDIM, HDIM);
        // 2c. conv + silu
        conv_silu<<<dim3(EDIM / 256, LSEQ), 256, 0, stream>>>(
            xz, conv_w + (size_t)i * EDIM * KCONV, conv_b + (size_t)i * EDIM, u);
        // 2d. x_proj split-K tiled GEMM: dbc = u @ xp_w^T   (N=80, K=1536)
        xproj_gemm<<<dim3(2, LSEQ / TS, KSPLIT), 256, 0, stream>>>(
            u, x_proj + (size_t)i * 80 * EDIM, part);
        reduce_dbc<<<LSEQ * 80 / 256, 256, 0, stream>>>(part, dbc);
        // 2e. dt = softplus(dbc[:, :48] @ dt_w^T + dt_b)
        gemm_nt_f32<true, true><<<dim3(EDIM / TS, LSEQ / TS), 256, 0, stream>>>(
            dbc, 80, dt_w + (size_t)i * EDIM * RDIM, RDIM, dt_b + (size_t)i * EDIM, dtb,
            LSEQ, EDIM, RDIM);
        // 2f-h. selective scan (chunked)
        const float* al = A_log + (size_t)i * EDIM * NDIM;
        scan_pass1<<<dim3(EDIM / 16, NCHUNK), 256, 0, stream>>>(dtb, u, dbc, al, chunkS, sumdt);
        scan_pass2<<<EDIM * NDIM / 256, 256, 0, stream>>>(chunkS, sumdt, al, sInit);
        scan_pass3<<<dim3(EDIM / 16, NCHUNK), 256, 0, stream>>>(
            dtb, u, dbc, xz, al, Dp + (size_t)i * EDIM, sInit, yzb);
        // 2i. out_proj: h = yz @ out_w^T   (N=768, K=1536); last layer also bf16 copy
        if (i == NLAYER - 1)
            gemm_mfma<false, true><<<dim3(HDIM / 64, LSEQ / 64), 256, 0, stream>>>(
                yzb, EDIM, out_wb, EDIM, nullptr, h, hb, LSEQ, HDIM, EDIM);
        else
            gemm_mfma<false, false><<<dim3(HDIM / 64, LSEQ / 64), 256, 0, stream>>>(
                yzb, EDIM, out_wb, EDIM, nullptr, h, nullptr, LSEQ, HDIM, EDIM);
    }

    // 3. head: out = h @ head_w^T + head_b  (N=256, K=768)
    gemm_mfma<true, false><<<dim3(SDIM / 64, LSEQ / 64), 256, 0, stream>>>(
        hb, HDIM, head_wb, HDIM, head_b, out, nullptr, LSEQ, SDIM, HDIM);
}

// Round 6
// 439.290 us; speedup vs baseline: 3.2861x; 1.1951x over previous
//
#include <hip/hip_runtime.h>
#include <hip/hip_bf16.h>
#include <math.h>

// Problem dims
#define SDIM 256
#define HDIM 768
#define EDIM 1536
#define NDIM 16
#define KCONV 4
#define RDIM 48
#define NLAYER 2
#define LSEQ 1024

#define NCHUNK 64
#define CHLEN (LSEQ / NCHUNK)   // 16

typedef __hip_bfloat16 bf16;
typedef __attribute__((ext_vector_type(8))) short short8;   // 8 bf16 = 4 VGPRs
typedef __attribute__((ext_vector_type(4))) float f32x4;

__device__ __forceinline__ float softplusf(float x) {
    return (x > 20.f) ? x : log1pf(expf(x));
}
__device__ __forceinline__ float siluf(float x) {
    return x / (1.f + expf(-x));
}

// ---------------- fp32 -> bf16 convert ----------------
__global__ __launch_bounds__(256) void f2b(const float* __restrict__ in,
                                           bf16* __restrict__ out, int n)
{
    int i = (blockIdx.x * 256 + threadIdx.x) * 4;
    if (i + 3 < n) {
        float4 v = *(const float4*)(in + i);
        out[i + 0] = (bf16)v.x; out[i + 1] = (bf16)v.y;
        out[i + 2] = (bf16)v.z; out[i + 3] = (bf16)v.w;
    } else {
        for (int k = i; k < n; k++) out[k] = (bf16)in[k];
    }
}

// ---------------- MFMA bf16 GEMM: out[M,N] = A[M,K] @ W[N,K]^T ----------------
template<bool BIAS, bool OUTB>
__global__ __launch_bounds__(256) void gemm_mfma(
    const bf16* __restrict__ A, int lda,
    const bf16* __restrict__ W, int ldw,
    const float* __restrict__ bias,
    float* __restrict__ out, bf16* __restrict__ outb,
    int M, int N, int Kd)
{
    __shared__ __align__(16) short As[64][72];   // +8 pad: 2-way bank alias only
    __shared__ __align__(16) short Ws[64][72];

    const int tid  = threadIdx.x;
    const int lane = tid & 63;
    const int wid  = tid >> 6;
    const int wm   = wid >> 1, wn = wid & 1;      // 2x2 wave grid
    const int row0 = blockIdx.y * 64, col0 = blockIdx.x * 64;
    const int quad = lane >> 4;                   // 0..3
    const int l16  = lane & 15;

    f32x4 acc[2][2] = {};

    for (int k0 = 0; k0 < Kd; k0 += 64) {
        #pragma unroll
        for (int i = 0; i < 2; i++) {
            int id = tid + i * 256;
            int r = id >> 3, g = id & 7;
            *(uint4*)&As[r][g * 8] =
                *(const uint4*)(A + (size_t)(row0 + r) * lda + k0 + g * 8);
            *(uint4*)&Ws[r][g * 8] =
                *(const uint4*)(W + (size_t)(col0 + r) * ldw + k0 + g * 8);
        }
        __syncthreads();
        #pragma unroll
        for (int ks = 0; ks < 64; ks += 32) {
            short8 af[2], bf[2];
            #pragma unroll
            for (int i = 0; i < 2; i++)
                af[i] = *(const short8*)&As[wm * 32 + i * 16 + l16][ks + quad * 8];
            #pragma unroll
            for (int j = 0; j < 2; j++)
                bf[j] = *(const short8*)&Ws[wn * 32 + j * 16 + l16][ks + quad * 8];
            #pragma unroll
            for (int i = 0; i < 2; i++)
                #pragma unroll
                for (int j = 0; j < 2; j++)
                    acc[i][j] = __builtin_amdgcn_mfma_f32_16x16x32_bf16(
                        af[i], bf[j], acc[i][j], 0, 0, 0);
        }
        __syncthreads();
    }

    // C layout: col = lane&15, row = quad*4 + reg
    #pragma unroll
    for (int i = 0; i < 2; i++) {
        #pragma unroll
        for (int j = 0; j < 2; j++) {
            int gn = col0 + wn * 32 + j * 16 + l16;
            int gm0 = row0 + wm * 32 + i * 16 + quad * 4;
            #pragma unroll
            for (int r = 0; r < 4; r++) {
                float v = acc[i][j][r];
                if (BIAS) v += bias[gn];
                size_t o = (size_t)(gm0 + r) * N + gn;
                out[o] = v;
                if (OUTB) outb[o] = (bf16)v;
            }
        }
    }
}

// ---------------- fp32 tiled NT GEMM (dt_proj: K=48) ----------------
#define TS 64
#define KT 16

template<bool BIAS, bool SOFTPLUS>
__global__ __launch_bounds__(256) void gemm_nt_f32(
    const float* __restrict__ A, int lda,
    const float* __restrict__ W, int ldw,
    const float* __restrict__ bias,
    float* __restrict__ out, int M, int N, int Kd)
{
    __shared__ float As[KT][TS + 4];
    __shared__ float Ws[KT][TS + 4];
    const int tid = threadIdx.x;
    const int tx = tid & 15, ty = tid >> 4;
    const int tx4 = tx * 4, ty4 = ty * 4;
    const int row0 = blockIdx.y * TS, col0 = blockIdx.x * TS;

    float acc[4][4] = {};

    for (int k0 = 0; k0 < Kd; k0 += KT) {
        #pragma unroll
        for (int i = 0; i < 4; i++) {
            int idx = tid + i * 256;
            int m = idx >> 4, kk = idx & 15;
            int gm = row0 + m, gk = k0 + kk;
            float v = 0.f;
            if (gm < M && gk < Kd) v = A[(size_t)gm * lda + gk];
            As[kk][m] = v;
        }
        #pragma unroll
        for (int i = 0; i < 4; i++) {
            int idx = tid + i * 256;
            int nn = idx >> 4, kk = idx & 15;
            int gn = col0 + nn, gk = k0 + kk;
            float v = 0.f;
            if (gn < N && gk < Kd) v = W[(size_t)gn * ldw + gk];
            Ws[kk][nn] = v;
        }
        __syncthreads();
        #pragma unroll
        for (int kk = 0; kk < KT; kk++) {
            float a[4], b[4];
            #pragma unroll
            for (int i = 0; i < 4; i++) a[i] = As[kk][ty4 + i];
            #pragma unroll
            for (int j = 0; j < 4; j++) b[j] = Ws[kk][tx4 + j];
            #pragma unroll
            for (int i = 0; i < 4; i++)
                #pragma unroll
                for (int j = 0; j < 4; j++)
                    acc[i][j] += a[i] * b[j];
        }
        __syncthreads();
    }

    #pragma unroll
    for (int i = 0; i < 4; i++) {
        int gm = row0 + ty4 + i;
        if (gm >= M) continue;
        #pragma unroll
        for (int j = 0; j < 4; j++) {
            int gn = col0 + tx4 + j;
            if (gn >= N) continue;
            float v = acc[i][j];
            if (BIAS) v += bias[gn];
            if (SOFTPLUS) v = softplusf(v);
            out[(size_t)gm * N + gn] = v;
        }
    }
}

// ---------------- x_proj: split-K LDS-tiled fp32 GEMM ----------------
#define KSPLIT 8
#define KCH (EDIM / KSPLIT)   // 192

__global__ __launch_bounds__(256) void xproj_gemm(
    const float* __restrict__ u, const float* __restrict__ xw,
    float* __restrict__ part)
{
    __shared__ float As[KT][TS + 4];
    __shared__ float Ws[KT][TS + 4];
    const int tid = threadIdx.x;
    const int tx = tid & 15, ty = tid >> 4;
    const int tx4 = tx * 4, ty4 = ty * 4;
    const int row0 = blockIdx.y * TS, col0 = blockIdx.x * TS;
    const int kbase = blockIdx.z * KCH;

    float acc[4][4] = {};

    for (int k0 = 0; k0 < KCH; k0 += KT) {
        #pragma unroll
        for (int i = 0; i < 4; i++) {
            int idx = tid + i * 256;
            int m = idx >> 4, kk = idx & 15;
            As[kk][m] = u[(size_t)(row0 + m) * EDIM + kbase + k0 + kk];
        }
        #pragma unroll
        for (int i = 0; i < 4; i++) {
            int idx = tid + i * 256;
            int nn = idx >> 4, kk = idx & 15;
            int gn = col0 + nn;
            float v = 0.f;
            if (gn < 80) v = xw[(size_t)gn * EDIM + kbase + k0 + kk];
            Ws[kk][nn] = v;
        }
        __syncthreads();
        #pragma unroll
        for (int kk = 0; kk < KT; kk++) {
            float a[4], b[4];
            #pragma unroll
            for (int i = 0; i < 4; i++) a[i] = As[kk][ty4 + i];
            #pragma unroll
            for (int j = 0; j < 4; j++) b[j] = Ws[kk][tx4 + j];
            #pragma unroll
            for (int i = 0; i < 4; i++)
                #pragma unroll
                for (int j = 0; j < 4; j++)
                    acc[i][j] += a[i] * b[j];
        }
        __syncthreads();
    }

    float* pdst = part + (size_t)blockIdx.z * (LSEQ * 80);
    #pragma unroll
    for (int i = 0; i < 4; i++) {
        int gm = row0 + ty4 + i;
        #pragma unroll
        for (int j = 0; j < 4; j++) {
            int gn = col0 + tx4 + j;
            if (gn < 80) pdst[(size_t)gm * 80 + gn] = acc[i][j];
        }
    }
}

__global__ __launch_bounds__(256) void reduce_dbc(
    const float* __restrict__ part, float* __restrict__ dbc)
{
    int idx = blockIdx.x * 256 + threadIdx.x;     // 0 .. 1024*80-1
    float s = 0.f;
    #pragma unroll
    for (int k = 0; k < KSPLIT; k++) s += part[(size_t)k * (LSEQ * 80) + idx];
    dbc[idx] = s;
}

// ---------------- Residual add + RMSNorm -> bf16 ----------------
__global__ __launch_bounds__(256) void rmsnorm_res(
    const float* __restrict__ h, float* __restrict__ res, bf16* __restrict__ hnb,
    const float* __restrict__ w, int first)
{
    const int t = blockIdx.x;
    const int tid = threadIdx.x;
    float v[3];
    float ss = 0.f;
    #pragma unroll
    for (int r = 0; r < 3; r++) {
        int j = tid + r * 256;
        float x = h[(size_t)t * HDIM + j];
        if (!first) x += res[(size_t)t * HDIM + j];
        v[r] = x;
        res[(size_t)t * HDIM + j] = x;
        ss += x * x;
    }
    #pragma unroll
    for (int m = 32; m >= 1; m >>= 1) ss += __shfl_down(ss, m);
    __shared__ float red[4];
    int wid = tid >> 6;
    if ((tid & 63) == 0) red[wid] = ss;
    __syncthreads();
    __shared__ float stot;
    if (tid == 0) stot = red[0] + red[1] + red[2] + red[3];
    __syncthreads();
    float scale = rsqrtf(stot / (float)HDIM + 1e-5f);
    #pragma unroll
    for (int r = 0; r < 3; r++) {
        int j = tid + r * 256;
        hnb[(size_t)t * HDIM + j] = (bf16)(v[r] * scale * w[j]);
    }
}

// ---------------- Depthwise causal conv1d + SiLU ----------------
__global__ __launch_bounds__(256) void conv_silu(
    const float* __restrict__ xz, const float* __restrict__ cw,
    const float* __restrict__ cb, float* __restrict__ u)
{
    const int e = blockIdx.x * 256 + threadIdx.x;
    const int t = blockIdx.y;
    float s = cb[e];
    #pragma unroll
    for (int k = 0; k < KCONV; k++) {
        int tt = t - (KCONV - 1) + k;
        if (tt >= 0) s += cw[e * KCONV + k] * xz[(size_t)tt * (2 * EDIM) + e];
    }
    u[(size_t)t * EDIM + e] = siluf(s);
}

// ---------------- Selective scan, chunked: thread per e, N=16 states in regs ----
// pass1: local scan from zero init -> chunkS[c][e][n]; sumdt[c][e]
__global__ __launch_bounds__(256) void scan_pass1(
    const float* __restrict__ dt, const float* __restrict__ u,
    const float* __restrict__ dbc, const float* __restrict__ a_log,
    float* __restrict__ chunkS, float* __restrict__ sumdt)
{
    const int e = blockIdx.x * 256 + threadIdx.x;
    const int c = blockIdx.y;
    float A[16];
    #pragma unroll
    for (int q = 0; q < 4; q++) {
        float4 a4 = *(const float4*)(a_log + e * NDIM + q * 4);
        A[q * 4 + 0] = -__expf(a4.x); A[q * 4 + 1] = -__expf(a4.y);
        A[q * 4 + 2] = -__expf(a4.z); A[q * 4 + 3] = -__expf(a4.w);
    }
    float s[16] = {};
    float sd = 0.f;
    const int t0 = c * CHLEN;
    #pragma unroll 2
    for (int t = t0; t < t0 + CHLEN; t++) {
        float dtv = dt[(size_t)t * EDIM + e];
        float uv  = u[(size_t)t * EDIM + e];
        float dtu = dtv * uv;
        sd += dtv;
        float4 B4[4];
        #pragma unroll
        for (int q = 0; q < 4; q++)
            B4[q] = *(const float4*)(dbc + (size_t)t * 80 + RDIM + q * 4);
        const float* B = (const float*)B4;
        #pragma unroll
        for (int n = 0; n < 16; n++)
            s[n] = s[n] * __expf(dtv * A[n]) + dtu * B[n];
    }
    float* cs = chunkS + ((size_t)c * EDIM + e) * NDIM;
    #pragma unroll
    for (int q = 0; q < 4; q++)
        *(float4*)(cs + q * 4) = make_float4(s[q*4+0], s[q*4+1], s[q*4+2], s[q*4+3]);
    sumdt[(size_t)c * EDIM + e] = sd;
}

// pass2: cross-chunk combine -> sInit[c][e][n]
__global__ __launch_bounds__(256) void scan_pass2(
    const float* __restrict__ chunkS, const float* __restrict__ sumdt,
    const float* __restrict__ a_log, float* __restrict__ sInit)
{
    const int idx = blockIdx.x * 256 + threadIdx.x;  // 0..E*N-1
    const int n = idx & 15, e = idx >> 4;
    const float Aen = -__expf(a_log[idx]);
    float s = 0.f;
    for (int c = 0; c < NCHUNK; c++) {
        sInit[((size_t)c * EDIM + e) * NDIM + n] = s;
        float P = __expf(Aen * sumdt[(size_t)c * EDIM + e]);
        s = s * P + chunkS[((size_t)c * EDIM + e) * NDIM + n];
    }
}

// pass3: re-run chunk with correct init; yz[t][e] = (y + u*D) * silu(z), bf16
__global__ __launch_bounds__(256) void scan_pass3(
    const float* __restrict__ dt, const float* __restrict__ u,
    const float* __restrict__ dbc, const float* __restrict__ xz,
    const float* __restrict__ a_log, const float* __restrict__ Dp,
    const float* __restrict__ sInit, bf16* __restrict__ yzb)
{
    const int e = blockIdx.x * 256 + threadIdx.x;
    const int c = blockIdx.y;
    float A[16];
    #pragma unroll
    for (int q = 0; q < 4; q++) {
        float4 a4 = *(const float4*)(a_log + e * NDIM + q * 4);
        A[q * 4 + 0] = -__expf(a4.x); A[q * 4 + 1] = -__expf(a4.y);
        A[q * 4 + 2] = -__expf(a4.z); A[q * 4 + 3] = -__expf(a4.w);
    }
    const float dv = Dp[e];
    float s[16];
    const float* si = sInit + ((size_t)c * EDIM + e) * NDIM;
    #pragma unroll
    for (int q = 0; q < 4; q++) {
        float4 s4 = *(const float4*)(si + q * 4);
        s[q*4+0] = s4.x; s[q*4+1] = s4.y; s[q*4+2] = s4.z; s[q*4+3] = s4.w;
    }
    const int t0 = c * CHLEN;
    #pragma unroll 2
    for (int t = t0; t < t0 + CHLEN; t++) {
        float dtv = dt[(size_t)t * EDIM + e];
        float uv  = u[(size_t)t * EDIM + e];
        float zv  = xz[(size_t)t * (2 * EDIM) + EDIM + e];
        float dtu = dtv * uv;
        float4 B4[4], C4[4];
        #pragma unroll
        for (int q = 0; q < 4; q++) {
            B4[q] = *(const float4*)(dbc + (size_t)t * 80 + RDIM + q * 4);
            C4[q] = *(const float4*)(dbc + (size_t)t * 80 + RDIM + NDIM + q * 4);
        }
        const float* B = (const float*)B4;
        const float* C = (const float*)C4;
        float y = 0.f;
        #pragma unroll
        for (int n = 0; n < 16; n++) {
            s[n] = s[n] * __expf(dtv * A[n]) + dtu * B[n];
            y += s[n] * C[n];
        }
        y += uv * dv;
        yzb[(size_t)t * EDIM + e] = (bf16)(y * siluf(zv));
    }
}

extern "C" void kernel_launch(void* const* d_in, const int* in_sizes, int n_in,
                              void* d_out, int out_size, void* d_ws, size_t ws_size,
                              hipStream_t stream)
{
    const float* x        = (const float*)d_in[0];
    const float* emb_w    = (const float*)d_in[1];
    const float* emb_b    = (const float*)d_in[2];
    const float* norm_w   = (const float*)d_in[3];
    const float* in_proj  = (const float*)d_in[4];
    const float* conv_w   = (const float*)d_in[5];
    const float* conv_b   = (const float*)d_in[6];
    const float* x_proj   = (const float*)d_in[7];
    const float* dt_w     = (const float*)d_in[8];
    const float* dt_b     = (const float*)d_in[9];
    const float* A_log    = (const float*)d_in[10];
    const float* Dp       = (const float*)d_in[11];
    const float* out_proj = (const float*)d_in[12];
    const float* head_w   = (const float*)d_in[13];
    const float* head_b   = (const float*)d_in[14];
    float* out = (float*)d_out;

    float* ws = (float*)d_ws;
    size_t off = 0;
    float* h      = ws + off; off += (size_t)LSEQ * HDIM;
    float* res    = ws + off; off += (size_t)LSEQ * HDIM;
    float* xz     = ws + off; off += (size_t)LSEQ * 2 * EDIM;
    float* u      = ws + off; off += (size_t)LSEQ * EDIM;
    float* dbc    = ws + off; off += (size_t)LSEQ * 80;
    float* part   = ws + off; off += (size_t)KSPLIT * LSEQ * 80;
    float* dtb    = ws + off; off += (size_t)LSEQ * EDIM;
    float* chunkS = ws + off; off += (size_t)NCHUNK * EDIM * NDIM;
    float* sumdt  = ws + off; off += (size_t)NCHUNK * EDIM;
    float* sInit  = ws + off; off += (size_t)NCHUNK * EDIM * NDIM;
    // bf16 buffers (2 bytes) — carve from remaining fp32 words
    bf16* hnb     = (bf16*)(ws + off); off += (size_t)LSEQ * HDIM / 2;
    bf16* yzb     = (bf16*)(ws + off); off += (size_t)LSEQ * EDIM / 2;
    bf16* hb      = (bf16*)(ws + off); off += (size_t)LSEQ * HDIM / 2;
    bf16* xb      = (bf16*)(ws + off); off += (size_t)LSEQ * SDIM / 2;
    bf16* emb_wb  = (bf16*)(ws + off); off += (size_t)HDIM * SDIM / 2;
    bf16* head_wb = (bf16*)(ws + off); off += (size_t)SDIM * HDIM / 2;
    bf16* in_wb   = (bf16*)(ws + off); off += (size_t)2 * EDIM * HDIM / 2;
    bf16* out_wb  = (bf16*)(ws + off); off += (size_t)HDIM * EDIM / 2;

    // weight / input conversions (layer-invariant)
    f2b<<<(LSEQ * SDIM / 4 + 255) / 256, 256, 0, stream>>>(x, xb, LSEQ * SDIM);
    f2b<<<(HDIM * SDIM / 4 + 255) / 256, 256, 0, stream>>>(emb_w, emb_wb, HDIM * SDIM);
    f2b<<<(SDIM * HDIM / 4 + 255) / 256, 256, 0, stream>>>(head_w, head_wb, SDIM * HDIM);

    // 1. embed: h = x @ emb_w^T + emb_b   (M=1024, N=768, K=256)
    gemm_mfma<true, false><<<dim3(HDIM / 64, LSEQ / 64), 256, 0, stream>>>(
        xb, SDIM, emb_wb, SDIM, emb_b, h, nullptr, LSEQ, HDIM, SDIM);

    for (int i = 0; i < NLAYER; i++) {
        f2b<<<(2 * EDIM * HDIM / 4 + 255) / 256, 256, 0, stream>>>(
            in_proj + (size_t)i * 2 * EDIM * HDIM, in_wb, 2 * EDIM * HDIM);
        f2b<<<(HDIM * EDIM / 4 + 255) / 256, 256, 0, stream>>>(
            out_proj + (size_t)i * HDIM * EDIM, out_wb, HDIM * EDIM);

        // 2a. residual + rmsnorm -> bf16
        rmsnorm_res<<<LSEQ, 256, 0, stream>>>(h, res, hnb, norm_w + (size_t)i * HDIM, i == 0);
        // 2b. in_proj: xz = hn @ in_w^T   (N=3072, K=768)
        gemm_mfma<false, false><<<dim3(2 * EDIM / 64, LSEQ / 64), 256, 0, stream>>>(
            hnb, HDIM, in_wb, HDIM, nullptr, xz, nullptr, LSEQ, 2 * EDIM, HDIM);
        // 2c. conv + silu
        conv_silu<<<dim3(EDIM / 256, LSEQ), 256, 0, stream>>>(
            xz, conv_w + (size_t)i * EDIM * KCONV, conv_b + (size_t)i * EDIM, u);
        // 2d. x_proj split-K tiled GEMM: dbc = u @ xp_w^T   (N=80, K=1536)
        xproj_gemm<<<dim3(2, LSEQ / TS, KSPLIT), 256, 0, stream>>>(
            u, x_proj + (size_t)i * 80 * EDIM, part);
        reduce_dbc<<<LSEQ * 80 / 256, 256, 0, stream>>>(part, dbc);
        // 2e. dt = softplus(dbc[:, :48] @ dt_w^T + dt_b)
        gemm_nt_f32<true, true><<<dim3(EDIM / TS, LSEQ / TS), 256, 0, stream>>>(
            dbc, 80, dt_w + (size_t)i * EDIM * RDIM, RDIM, dt_b + (size_t)i * EDIM, dtb,
            LSEQ, EDIM, RDIM);
        // 2f-h. selective scan (chunked, thread-per-e)
        const float* al = A_log + (size_t)i * EDIM * NDIM;
        scan_pass1<<<dim3(EDIM / 256, NCHUNK), 256, 0, stream>>>(dtb, u, dbc, al, chunkS, sumdt);
        scan_pass2<<<EDIM * NDIM / 256, 256, 0, stream>>>(chunkS, sumdt, al, sInit);
        scan_pass3<<<dim3(EDIM / 256, NCHUNK), 256, 0, stream>>>(
            dtb, u, dbc, xz, al, Dp + (size_t)i * EDIM, sInit, yzb);
        // 2i. out_proj: h = yz @ out_w^T   (N=768, K=1536); last layer also bf16 copy
        if (i == NLAYER - 1)
            gemm_mfma<false, true><<<dim3(HDIM / 64, LSEQ / 64), 256, 0, stream>>>(
                yzb, EDIM, out_wb, EDIM, nullptr, h, hb, LSEQ, HDIM, EDIM);
        else
            gemm_mfma<false, false><<<dim3(HDIM / 64, LSEQ / 64), 256, 0, stream>>>(
                yzb, EDIM, out_wb, EDIM, nullptr, h, nullptr, LSEQ, HDIM, EDIM);
    }

    // 3. head: out = h @ head_w^T + head_b  (N=256, K=768)
    gemm_mfma<true, false><<<dim3(SDIM / 64, LSEQ / 64), 256, 0, stream>>>(
        hb, HDIM, head_wb, HDIM, head_b, out, nullptr, LSEQ, SDIM, HDIM);
}